// Round 6
// baseline (464.625 us; speedup 1.0000x reference)
//
#include <hip/hip_runtime.h>

typedef __attribute__((ext_vector_type(8))) short v8s;
typedef __attribute__((ext_vector_type(8))) unsigned short v8u;
typedef __attribute__((ext_vector_type(4))) unsigned short v4u;
typedef __attribute__((ext_vector_type(4))) float f32x4;

#define DEV __device__ __forceinline__

DEV unsigned short f2bf(float f) {
  union { float f; unsigned u; } v; v.f = f;
  unsigned r = v.u + 0x7fffu + ((v.u >> 16) & 1u);
  return (unsigned short)(r >> 16);
}

DEV void gload16(const unsigned short* g, unsigned short* l) {
  __builtin_amdgcn_global_load_lds(
      (const __attribute__((address_space(1))) unsigned int*)g,
      (__attribute__((address_space(3))) unsigned int*)l, 16, 0, 0);
}

#define SL2E 0.1803368801111204f  // 0.125 * log2(e)

// ------------------------------------------------------------------
// LayerNorm -> bf16
// ------------------------------------------------------------------
__global__ __launch_bounds__(256) void ln_kernel(
    const float* __restrict__ x, unsigned short* __restrict__ h,
    const float* __restrict__ alpha, const float* __restrict__ beta)
{
  int row = blockIdx.x;
  int tid = threadIdx.x;
  const float4* xr = reinterpret_cast<const float4*>(x + (size_t)row * 1024);
  float4 v = xr[tid];
  float s  = v.x + v.y + v.z + v.w;
  float ss = v.x * v.x + v.y * v.y + v.z * v.z + v.w * v.w;
#pragma unroll
  for (int off = 1; off < 64; off <<= 1) {
    s  += __shfl_xor(s, off);
    ss += __shfl_xor(ss, off);
  }
  __shared__ float ps[4][2];
  int wid = tid >> 6, lane = tid & 63;
  if (lane == 0) { ps[wid][0] = s; ps[wid][1] = ss; }
  __syncthreads();
  s  = ps[0][0] + ps[1][0] + ps[2][0] + ps[3][0];
  ss = ps[0][1] + ps[1][1] + ps[2][1] + ps[3][1];
  float mean = s * (1.0f / 1024.0f);
  float var  = (ss - 1024.0f * mean * mean) * (1.0f / 1023.0f);
  float inv  = 1.0f / (sqrtf(fmaxf(var, 0.0f)) + 1e-6f);
  float a = alpha[0], b = beta[0];
  v4u o;
  o[0] = f2bf(a * ((v.x - mean) * inv) + b);
  o[1] = f2bf(a * ((v.y - mean) * inv) + b);
  o[2] = f2bf(a * ((v.z - mean) * inv) + b);
  o[3] = f2bf(a * ((v.w - mean) * inv) + b);
  *reinterpret_cast<v4u*>(h + (size_t)row * 1024 + tid * 4) = o;
}

// ------------------------------------------------------------------
// fp32 W[K][N] -> bf16 Wt[N][K]
// ------------------------------------------------------------------
__global__ __launch_bounds__(256) void transpose_convert(
    const float* __restrict__ W, unsigned short* __restrict__ Wt, int K, int N)
{
  __shared__ float t[32][33];
  int n0 = blockIdx.x * 32, k0 = blockIdx.y * 32;
  int tx = threadIdx.x, ty = threadIdx.y;
#pragma unroll
  for (int i = 0; i < 4; ++i)
    t[ty + i * 8][tx] = W[(size_t)(k0 + ty + i * 8) * N + n0 + tx];
  __syncthreads();
#pragma unroll
  for (int i = 0; i < 4; ++i)
    Wt[(size_t)(n0 + ty + i * 8) * K + k0 + tx] = f2bf(t[tx][ty + i * 8]);
}

// ------------------------------------------------------------------
// Ring-4 pipelined bf16 GEMM. BK=32 slices, 4 LDS buffers, depth-3
// prefetch with counted vmcnt, 8 waves; BM=256: per-wave 128x64.
// Row-pair LDS layout: granule(r,g) at [r>>1][((r&1)*4+g)^((r>>1)&7)]
// -> frag reads 2-way max conflict, lane-constant immediate offsets.
// ------------------------------------------------------------------
enum { MODE_QKV = 0, MODE_RES = 2, MODE_FFN1 = 3 };

template <int MODE, int BM>
__global__ __launch_bounds__(512, 2) void gemm_ring(
    const unsigned short* __restrict__ A, const unsigned short* __restrict__ Bt,
    const float* __restrict__ bias0, const float* __restrict__ bias1,
    const float* __restrict__ bias2, const float* __restrict__ resid,
    void* __restrict__ o0, void* __restrict__ o1, void* __restrict__ o2,
    int M, int N, int K)
{
  constexpr int MF = (BM == 256) ? 8 : 4;     // m-frags per wave
  constexpr int CA = BM / 128;                // A stage calls per thread
  constexpr int LOADS = CA + 2;               // gloads per thread per tile
  constexpr int AELEMS = BM * 32;
  constexpr int BUFE = (BM + 256) * 32;
  constexpr int WROWS = BM / 2;
  __shared__ unsigned short lds[4 * BUFE];

  int nbx = M / BM, nwg = gridDim.x;
  int lin = blockIdx.x;
  int qq = nwg >> 3, rr = nwg & 7;
  int xcd = lin & 7, idx = lin >> 3;
  int swz = (xcd < rr ? xcd * (qq + 1) : rr * (qq + 1) + (xcd - rr) * qq) + idx;
  int bx = swz % nbx, by = swz / nbx;

  int tid = threadIdx.x, lane = tid & 63, wid = tid >> 6;
  int wm = wid >> 2, wn = wid & 3;
  int g = lane >> 4, c0 = lane & 15;
  int rowBase = bx * BM, colBase = by * 256;

  const unsigned short* Ab = A  + (size_t)rowBase * K;
  const unsigned short* Bb = Bt + (size_t)colBase * K;
  int NT = K >> 5;

  // ---- staging source/dest precompute (lane-constant) ----
  const unsigned short* srcA[CA]; int dqA[CA];
  const unsigned short* srcB[2];  int dqB[2];
#pragma unroll
  for (int c = 0; c < CA; ++c) {
    int qg = c * 512 + wid * 64 + lane;
    int rp = qg >> 3, u = (qg & 7) ^ (rp & 7);
    srcA[c] = Ab + (size_t)(2 * rp + (u >> 2)) * K + (u & 3) * 8;
    dqA[c] = qg;
  }
#pragma unroll
  for (int c = 0; c < 2; ++c) {
    int qg = c * 512 + wid * 64 + lane;
    int rp = qg >> 3, u = (qg & 7) ^ (rp & 7);
    srcB[c] = Bb + (size_t)(2 * rp + (u >> 2)) * K + (u & 3) * 8;
    dqB[c] = qg;
  }

  // ---- fragment read bases (lane-constant, frag = +1024B) ----
  int u = ((c0 & 1) * 4 + g) ^ ((c0 >> 1) & 7);
  int abase = (wm * (WROWS / 2) + (c0 >> 1)) * 128 + u * 16;
  int bbase = (wn * 32 + (c0 >> 1)) * 128 + u * 16 + AELEMS * 2;

  f32x4 acc[MF][4];
#pragma unroll
  for (int m = 0; m < MF; ++m)
#pragma unroll
    for (int n = 0; n < 4; ++n) acc[m][n] = (f32x4){0.f, 0.f, 0.f, 0.f};

#define STAGE(tt) do { \
    unsigned short* sb_ = lds + ((tt) & 3) * BUFE; int ks_ = (tt) << 5; \
    _Pragma("unroll") for (int c = 0; c < CA; ++c) gload16(srcA[c] + ks_, sb_ + dqA[c] * 8); \
    _Pragma("unroll") for (int c = 0; c < 2;  ++c) gload16(srcB[c] + ks_, sb_ + AELEMS + dqB[c] * 8); \
  } while (0)

  STAGE(0); STAGE(1); STAGE(2);
  if constexpr (LOADS == 4) asm volatile("s_waitcnt vmcnt(8)" ::: "memory");
  else                      asm volatile("s_waitcnt vmcnt(6)" ::: "memory");
  __builtin_amdgcn_s_barrier();
  asm volatile("" ::: "memory");

  for (int t = 0; t < NT; ++t) {
    const char* buf = (const char*)(lds + (t & 3) * BUFE);
    v8s af[MF], bfr[4];
#pragma unroll
    for (int m = 0; m < MF; ++m)
      af[m] = *reinterpret_cast<const v8s*>(buf + abase + m * 1024);
#pragma unroll
    for (int n = 0; n < 4; ++n)
      bfr[n] = *reinterpret_cast<const v8s*>(buf + bbase + n * 1024);

    bool s3 = (t + 3 < NT);
    if (s3) STAGE(t + 3);

    __builtin_amdgcn_s_setprio(1);
#pragma unroll
    for (int m = 0; m < MF; ++m)
#pragma unroll
      for (int n = 0; n < 4; ++n)
        acc[m][n] = __builtin_amdgcn_mfma_f32_16x16x32_bf16(af[m], bfr[n], acc[m][n], 0, 0, 0);
    __builtin_amdgcn_s_setprio(0);

    if (s3) {
      if constexpr (LOADS == 4) asm volatile("s_waitcnt vmcnt(8)" ::: "memory");
      else                      asm volatile("s_waitcnt vmcnt(6)" ::: "memory");
    } else if (t + 2 < NT) {
      if constexpr (LOADS == 4) asm volatile("s_waitcnt vmcnt(4)" ::: "memory");
      else                      asm volatile("s_waitcnt vmcnt(3)" ::: "memory");
    } else if (t + 1 < NT) {
      asm volatile("s_waitcnt vmcnt(0)" ::: "memory");
    }
    __builtin_amdgcn_sched_barrier(0);
    __builtin_amdgcn_s_barrier();
    asm volatile("" ::: "memory");
  }
#undef STAGE

  // ---- epilogue ----
#pragma unroll
  for (int mf = 0; mf < MF; ++mf) {
#pragma unroll
    for (int nf = 0; nf < 4; ++nf) {
#pragma unroll
      for (int r = 0; r < 4; ++r) {
        int row = rowBase + wm * WROWS + mf * 16 + g * 4 + r;
        int col = colBase + wn * 64 + nf * 16 + c0;
        if constexpr (MODE == MODE_QKV) {
          int sect = colBase >> 10;            // block-uniform
          int cs = col & 1023;
          const float* bp = sect == 0 ? bias0 : (sect == 1 ? bias1 : bias2);
          float v = acc[mf][nf][r] + bp[cs];
          int hh = cs >> 6, d = cs & 63;
          int b = row >> 11, sI = row & 2047;
          size_t bh = (size_t)(b * 16 + hh);
          if (sect == 0) {
            ((unsigned short*)o0)[(bh * 2048 + sI) * 64 + d] = f2bf(v * SL2E);
          } else if (sect == 1) {
            ((unsigned short*)o1)[(bh * 2048 + sI) * 64 + d] = f2bf(v);
          } else {
            int k6 = sI & 63;
            int slot = ((k6 >> 5) << 5) | (((k6 >> 2) & 3) << 3) |
                       (((k6 >> 4) & 1) << 2) | (k6 & 3);
            int e = slot ^ ((d & 7) << 3);
            ((unsigned short*)o2)[((bh * 32 + (sI >> 6)) * 64 + d) * 64 + e] = f2bf(v);
          }
        } else if constexpr (MODE == MODE_RES) {
          float v = acc[mf][nf][r] + bias0[col];
          ((float*)o0)[(size_t)row * N + col] = resid[(size_t)row * N + col] + v;
        } else { // MODE_FFN1
          float v = acc[mf][nf][r] + bias0[col];
          ((unsigned short*)o0)[(size_t)row * N + col] = f2bf(fmaxf(v, 0.0f));
        }
      }
    }
  }
}

// ------------------------------------------------------------------
// Flash attention v4: swapped QK^T, double-buffered LDS, both K and
// (pre-permuted) V staged via global_load_lds, mask fast-path,
// defer-max softmax. Q pre-scaled by 0.125*log2(e) in producer.
// ------------------------------------------------------------------
__global__ __launch_bounds__(256) void attn_kernel(
    const unsigned short* __restrict__ q, const unsigned short* __restrict__ k,
    const unsigned short* __restrict__ vP, const int* __restrict__ mask,
    unsigned short* __restrict__ ctx)
{
  const int S = 2048, DK = 64, NT = 32;
  int bh = blockIdx.x;
  int b = bh >> 4, hh = bh & 15;
  int qbase = blockIdx.y * 64;
  int tid = threadIdx.x, lane = tid & 63, wid = tid >> 6;
  int g = lane >> 4, c0 = lane & 15;

  __shared__ unsigned short Ks[2][4096];
  __shared__ unsigned short Vs[2][4096];

  const unsigned short* qb  = q  + (size_t)bh * S * DK;
  const unsigned short* kb  = k  + (size_t)bh * S * DK;
  const unsigned short* vPb = vP + (size_t)bh * 32 * 4096;
  const int* mb = mask + b * S;

  int qrow = qbase + wid * 16 + c0;
  v8s aq[2];
#pragma unroll
  for (int t = 0; t < 2; ++t)
    aq[t] = *reinterpret_cast<const v8s*>(&qb[(size_t)qrow * DK + t * 32 + g * 8]);

  int i0 = tid, i1 = tid + 256;
  int r0 = i0 >> 3, m0 = i0 & 7;
  int r1 = i1 >> 3, m1 = i1 & 7;
  const unsigned short* ks0 = kb + (size_t)r0 * DK + 8 * (m0 ^ (r0 & 7));
  const unsigned short* ks1 = kb + (size_t)r1 * DK + 8 * (m1 ^ (r1 & 7));

  f32x4 acc[4];
#pragma unroll
  for (int no = 0; no < 4; ++no) acc[no] = (f32x4){0.f, 0.f, 0.f, 0.f};
  float mrow = -1e30f, lrow = 0.f;

  // prologue: stage tile 0
  gload16(ks0, &Ks[0][i0 * 8]);
  gload16(ks1, &Ks[0][i1 * 8]);
  gload16(vPb + i0 * 8, &Vs[0][i0 * 8]);
  gload16(vPb + i1 * 8, &Vs[0][i1 * 8]);
  __syncthreads();

  for (int t = 0; t < NT; ++t) {
    int cur = t & 1, nxt = cur ^ 1;
    if (t + 1 < NT) {
      int kofs = (t + 1) * 64 * DK;
      gload16(ks0 + kofs, &Ks[nxt][i0 * 8]);
      gload16(ks1 + kofs, &Ks[nxt][i1 * 8]);
      gload16(vPb + (t + 1) * 4096 + i0 * 8, &Vs[nxt][i0 * 8]);
      gload16(vPb + (t + 1) * 4096 + i1 * 8, &Vs[nxt][i1 * 8]);
    }
    int mv = mb[t * 64 + lane];
    bool allv = __all(mv != 0);

    // ---- QK^T (swapped): p[n*4+r] = S^T[k=n*16+g*4+r][q=c0] ----
    float p[16];
#pragma unroll
    for (int n = 0; n < 4; ++n) {
      f32x4 sa = (f32x4){0.f, 0.f, 0.f, 0.f};
      int kvr = n * 16 + c0;
      const char* krow = (const char*)&Ks[cur][kvr * DK];
      int sw = (kvr & 7) << 4;
#pragma unroll
      for (int tt = 0; tt < 2; ++tt) {
        v8s ak = *reinterpret_cast<const v8s*>(krow + ((tt * 64 + g * 16) ^ sw));
        sa = __builtin_amdgcn_mfma_f32_16x16x32_bf16(ak, aq[tt], sa, 0, 0, 0);
      }
#pragma unroll
      for (int r = 0; r < 4; ++r) p[n * 4 + r] = sa[r];
    }
    if (!allv) {
#pragma unroll
      for (int n = 0; n < 4; ++n) {
        int4 mm = *reinterpret_cast<const int4*>(&mb[t * 64 + n * 16 + g * 4]);
        p[n * 4 + 0] += mm.x ? 0.f : -1e9f;
        p[n * 4 + 1] += mm.y ? 0.f : -1e9f;
        p[n * 4 + 2] += mm.z ? 0.f : -1e9f;
        p[n * 4 + 3] += mm.w ? 0.f : -1e9f;
      }
    }

    // ---- online softmax (defer-max, THR=8, log2 domain) ----
    float pmax = p[0];
#pragma unroll
    for (int i = 1; i < 16; ++i) pmax = fmaxf(pmax, p[i]);
    pmax = fmaxf(pmax, __shfl_xor(pmax, 16));
    pmax = fmaxf(pmax, __shfl_xor(pmax, 32));
    if (!__all(pmax - mrow <= 8.0f)) {
      float mn = fmaxf(mrow, pmax);
      float sc = exp2f(mrow - mn);
      lrow *= sc;
#pragma unroll
      for (int no = 0; no < 4; ++no) {
        acc[no][0] *= sc; acc[no][1] *= sc; acc[no][2] *= sc; acc[no][3] *= sc;
      }
      mrow = mn;
    }
    float ts = 0.f;
#pragma unroll
    for (int i = 0; i < 16; ++i) { p[i] = exp2f(p[i] - mrow); ts += p[i]; }
    ts += __shfl_xor(ts, 16);
    ts += __shfl_xor(ts, 32);
    lrow += ts;

    // ---- pack P to bf16 ----
    v8s pbv[2];
#pragma unroll
    for (int c = 0; c < 2; ++c) {
      union { v8s s; unsigned u[4]; } pk;
#pragma unroll
      for (int hph = 0; hph < 4; ++hph)
        asm("v_cvt_pk_bf16_f32 %0, %1, %2"
            : "=v"(pk.u[hph]) : "v"(p[c * 8 + 2 * hph]), "v"(p[c * 8 + 2 * hph + 1]));
      pbv[c] = pk.s;
    }

    // ---- PV: single b128 operand reads from permuted V ----
#pragma unroll
    for (int c = 0; c < 2; ++c) {
#pragma unroll
      for (int no = 0; no < 4; ++no) {
        int d = no * 16 + c0;
        v8s av = *reinterpret_cast<const v8s*>(
            (const char*)&Vs[cur][d * 64] + ((c * 64 + g * 16) ^ ((d & 7) << 4)));
        acc[no] = __builtin_amdgcn_mfma_f32_16x16x32_bf16(av, pbv[c], acc[no], 0, 0, 0);
      }
    }
    __syncthreads();
  }

  float inv = 1.0f / fmaxf(lrow, 1e-20f);
#pragma unroll
  for (int no = 0; no < 4; ++no) {
    v4u o;
    o[0] = f2bf(acc[no][0] * inv);
    o[1] = f2bf(acc[no][1] * inv);
    o[2] = f2bf(acc[no][2] * inv);
    o[3] = f2bf(acc[no][3] * inv);
    *reinterpret_cast<v4u*>(
        &ctx[(size_t)(b * S + qrow) * 1024 + hh * 64 + no * 16 + g * 4]) = o;
  }
}

// ------------------------------------------------------------------
extern "C" void kernel_launch(void* const* d_in, const int* in_sizes, int n_in,
                              void* d_out, int out_size, void* d_ws, size_t ws_size,
                              hipStream_t stream)
{
  (void)in_sizes; (void)n_in; (void)out_size; (void)ws_size;
  const float* x    = (const float*)d_in[0];
  const int*   mask = (const int*)d_in[1];
  const float* Wq = (const float*)d_in[2];  const float* bq = (const float*)d_in[3];
  const float* Wk = (const float*)d_in[4];  const float* bk = (const float*)d_in[5];
  const float* Wv = (const float*)d_in[6];  const float* bv = (const float*)d_in[7];
  const float* Wo = (const float*)d_in[8];  const float* bo = (const float*)d_in[9];
  const float* W1 = (const float*)d_in[10]; const float* b1 = (const float*)d_in[11];
  const float* W2 = (const float*)d_in[12]; const float* b2 = (const float*)d_in[13];
  const float* ln1a = (const float*)d_in[14]; const float* ln1b = (const float*)d_in[15];
  const float* ln2a = (const float*)d_in[16]; const float* ln2b = (const float*)d_in[17];

  char* ws = (char*)d_ws;
  const size_t MB = (size_t)1 << 20;
  unsigned short* wqkvT = (unsigned short*)(ws + 0 * MB);  // [3072][1024]
  unsigned short* woT = (unsigned short*)(ws + 6 * MB);    // [1024][1024]
  unsigned short* w1T = (unsigned short*)(ws + 8 * MB);    // [4096][1024]
  unsigned short* w2T = (unsigned short*)(ws + 16 * MB);   // [1024][4096]
  unsigned short* hb  = (unsigned short*)(ws + 24 * MB);   // LN out, 8192x1024
  unsigned short* qb  = (unsigned short*)(ws + 40 * MB);   // [bh][S][64], pre-scaled
  unsigned short* kb  = (unsigned short*)(ws + 56 * MB);   // [bh][S][64]
  unsigned short* vPb = (unsigned short*)(ws + 72 * MB);   // [bh][32][64][64] permuted
  unsigned short* ctx = (unsigned short*)(ws + 88 * MB);   // 8192x1024
  unsigned short* gb  = (unsigned short*)(ws + 40 * MB);   // FFN mid (aliases dead bufs)
  float* xout = (float*)d_out;

  dim3 tb(32, 8);
  transpose_convert<<<dim3(32, 32),  tb, 0, stream>>>(Wq, wqkvT,                 1024, 1024);
  transpose_convert<<<dim3(32, 32),  tb, 0, stream>>>(Wk, wqkvT + 1024 * 1024,   1024, 1024);
  transpose_convert<<<dim3(32, 32),  tb, 0, stream>>>(Wv, wqkvT + 2048 * 1024,   1024, 1024);
  transpose_convert<<<dim3(32, 32),  tb, 0, stream>>>(Wo, woT, 1024, 1024);
  transpose_convert<<<dim3(128, 32), tb, 0, stream>>>(W1, w1T, 1024, 4096);
  transpose_convert<<<dim3(32, 128), tb, 0, stream>>>(W2, w2T, 4096, 1024);

  ln_kernel<<<8192, 256, 0, stream>>>(x, hb, ln1a, ln1b);

  // QKV merged: M=8192, N=3072, K=1024 -> 32 x 12 = 384 WGs
  gemm_ring<MODE_QKV, 256><<<384, 512, 0, stream>>>(
      hb, wqkvT, bq, bk, bv, nullptr, qb, kb, vPb, 8192, 3072, 1024);

  attn_kernel<<<dim3(64, 32), 256, 0, stream>>>(qb, kb, vPb, mask, ctx);

  // WO: M=8192, N=1024, K=1024 -> BM=128: 64 x 4 = 256 WGs
  gemm_ring<MODE_RES, 128><<<256, 512, 0, stream>>>(
      ctx, woT, bo, nullptr, nullptr, x, xout, nullptr, nullptr, 8192, 1024, 1024);

  ln_kernel<<<8192, 256, 0, stream>>>(xout, hb, ln2a, ln2b);

  // FFN1: M=8192, N=4096, K=1024 -> BM=256: 32 x 16 = 512 WGs
  gemm_ring<MODE_FFN1, 256><<<512, 512, 0, stream>>>(
      hb, w1T, b1, nullptr, nullptr, nullptr, gb, nullptr, nullptr, 8192, 4096, 1024);

  // FFN2: M=8192, N=1024, K=4096 -> BM=128: 64 x 4 = 256 WGs
  gemm_ring<MODE_RES, 128><<<256, 512, 0, stream>>>(
      gb, w2T, b2, nullptr, nullptr, xout, xout, nullptr, nullptr, 8192, 1024, 4096);
}